// Round 5
// baseline (216.359 us; speedup 1.0000x reference)
//
#include <hip/hip_runtime.h>

// NCC forces, 192^3 fp32. Round 9: 1-barrier software-pipelined slice loop.
// R6-R8 post-mortem: LDS instr diet, bank patterns, LDS capacity all
// exonerated (time flat). Wall = ~3500 cyc/iter vs ~380 cyc VALU content:
// schedule-stall-bound (2 barriers x 17 iters, phases serialized within
// iter). This round: ONE barrier per region; x(k), y(k), emit(k), staging
// all concurrent on different waves:
//   x(k):   raw[k&1] -> xs[k&1], Tf[k%5]       (lanes 0-79)
//   y(k):   xs[(k-1)&1] -> box[k&1]            (lanes 96-255)
//   ingest: box[(k-1)&1] -> ring;  emit z=z0-6+k (all lanes)
//   commit: pref -> raw[(k+1)&1]; prefetch s_{k+2}
// Hazard audit (write -> read -> rewrite, each pair 1 barrier apart):
//   raw slot: w@k, r@k+1, w@k+2 | xs: w@k, r@k+1, w@k+2
//   Tf (5 slots): w@k, r@k+4, w@k+5 | box: w@k, r@k+1, w@k+2
// 18 barriers/block (was 34). Pipeline 1 deeper: cm/cf ring 6-deep.
// LDS: raw 7680 + xs[2][5][20][16] 12800 + Tf[5][18][20] 7200 +
//      box[2][16][5][20] 12800 = 40480 B -> 4 blocks/CU.

#define DD 192
#define HH 192
#define WW 192
#define NVOX (DD * HH * WW)
#define SLICE (HH * WW)
#define TS 16
#define RR 20            // staged rows (y: y0-2 .. y0+17)
#define RW 24            // staged row width (x: x0-4 .. x0+19)
#define ZSEG 12
#define NBX 12
#define NBY 12
#define NBZ 16
#define NBLK (NBX * NBY * NBZ)        // 2304
#define PER_XCD (NBLK / 8)            // 288

__global__ __launch_bounds__(256)
void ncc_forces_kernel(const float* __restrict__ mimg,
                       const float* __restrict__ fimg,
                       const int*   __restrict__ mmask,
                       const int*   __restrict__ fmask,
                       float* __restrict__ out)
{
    __shared__ float rawm[2][RR][RW];     // 3840 B
    __shared__ float rawf[2][RR][RW];     // 3840 B
    __shared__ float xs[2][5][RR][16];    // 12800 B [buf][field][yrow][xo]
    __shared__ float Tf[5][18][20];       // 7200 B  (m+f); stored row r <-> raw row r+1
    __shared__ float box[2][TS][5][20];   // 12800 B [pp][x][field][yout]

    // XCD swizzle: XCD k gets 288 consecutive logical blocks (2 z-slabs)
    const int b  = blockIdx.x;
    const int L  = (b & 7) * PER_XCD + (b >> 3);
    const int bz = L / (NBX * NBY);
    const int r_ = L - bz * (NBX * NBY);
    const int by = r_ / NBX;
    const int bx = r_ - by * NBX;

    const int tid = threadIdx.x;
    const int tx = tid & 15, ty = tid >> 4;
    const int x0 = bx * TS, y0 = by * TS, z0 = bz * ZSEG;

    // ---- staging roles: 240 lanes = 2 images x 20 rows x 6 quads ----
    const int  simg   = tid / 120;            // 0,1 stager; 2 idle
    const bool stager = (simg < 2);
    const int  st     = tid - simg * 120;
    const int  srow   = st / 6;
    const int  squad  = st - srow * 6;
    const int  sgy    = y0 - 2 + srow;
    const int  sgx    = x0 - 4 + 4 * squad;   // quads all-in or all-out (x0%16==0)
    const bool sin_   = (sgy >= 0) && (sgy < HH) && (sgx >= 0) && (sgx <= WW - 4);
    const float* sptr = (simg == 1) ? fimg : mimg;
    float* sldsb = (simg == 1) ? &rawf[0][0][0] : &rawm[0][0][0];
    const int  sloff  = srow * RW + 4 * squad;

    float4 pref = make_float4(0, 0, 0, 0);
    auto prefetch = [&](int zz) {
        pref = make_float4(0, 0, 0, 0);
        if (stager && sin_ && zz >= 0 && zz < DD)
            pref = *(const float4*)(sptr + ((size_t)zz * HH + sgy) * WW + sgx);
    };

    // per-thread rings
    float ring[5][5];
#pragma unroll
    for (int s = 0; s < 5; ++s)
#pragma unroll
        for (int f = 0; f < 5; ++f) ring[s][f] = 0.f;
    float cm[6] = {0, 0, 0, 0, 0, 0}, cf[6] = {0, 0, 0, 0, 0, 0};

    const int gx = x0 + tx, gy = y0 + ty;
    const int vbase = (z0 * HH + gy) * WW + gx;   // voxel index at z=z0
    int umN = 0, ufN = 0;                          // masks prefetched 1 region ahead

    // pre-loop: commit s_0 = z0-2 into raw[0]; stage s_1 into pref
    prefetch(z0 - 2);
    if (stager) *(float4*)(sldsb + 0 * (RR * RW) + sloff) = pref;
    prefetch(z0 - 1);

    for (int k = 0; k <= ZSEG + 5; ++k) {
        __syncthreads();   // the ONE barrier: all region-(k-1) LDS writes visible

        const int sw = k & 1;
        const int um = umN, uf = ufN;        // masks for THIS region's emit
        if (k >= 5 && k <= ZSEG + 4) {       // load masks for emit(k+1): z = z0-5+k
            const int vn = vbase + (k - 5) * SLICE;
            umN = __builtin_nontemporal_load(mmask + vn);
            ufN = __builtin_nontemporal_load(fmask + vn);
        }

        // ---- commit slice s_{k+1} into raw[(k+1)&1]; prefetch s_{k+2} ----
        // raw[(k+1)&1]'s last readers were region k-1 (barrier k between).
        if (stager) *(float4*)(sldsb + ((k + 1) & 1) * (RR * RW) + sloff) = pref;
        prefetch(z0 + k);                    // s_{k+2} = z0-2+(k+2)

        // ---- x-phase: slice s_k -> xs[k&1], Tf[k%5]  (lanes 0-79) ----
        if (tid < 80 && k <= ZSEG + 3) {
            const int yy = tid >> 2;          // 0..19
            const int t4 = (tid & 3) * 4;     // 0,4,8,12
            const float4 A0 = *(const float4*)&rawm[sw][yy][t4];
            const float4 A1 = *(const float4*)&rawm[sw][yy][t4 + 4];
            const float2 A2 = *(const float2*)&rawm[sw][yy][t4 + 8];
            const float4 B0 = *(const float4*)&rawf[sw][yy][t4];
            const float4 B1 = *(const float4*)&rawf[sw][yy][t4 + 4];
            const float2 B2 = *(const float2*)&rawf[sw][yy][t4 + 8];
            const float a[10]  = {A0.x, A0.y, A0.z, A0.w, A1.x, A1.y, A1.z, A1.w, A2.x, A2.y};
            const float bb[10] = {B0.x, B0.y, B0.z, B0.w, B1.x, B1.y, B1.z, B1.w, B2.x, B2.y};
            float p[10], s, w0, w1, w2, w3;
#pragma unroll
            for (int f = 0; f < 5; ++f) {
#pragma unroll
                for (int i = 2; i < 10; ++i) {
                    p[i] = (f == 0) ? a[i] : (f == 1) ? bb[i] :
                           (f == 2) ? a[i] * a[i] : (f == 3) ? bb[i] * bb[i] : a[i] * bb[i];
                }
                s = p[2] + p[3] + p[4] + p[5] + p[6]; w0 = s;
                s += p[7] - p[2]; w1 = s;
                s += p[8] - p[3]; w2 = s;
                s += p[9] - p[4]; w3 = s;
                *(float4*)&xs[sw][f][yy][t4] = make_float4(w0, w1, w2, w3);
            }
            // T rows 1..18 only (gradients never touch rows 0/19)
            if (yy >= 1 && yy <= 18) {
                const int tw = k % 5;
                *(float4*)&Tf[tw][yy - 1][t4] =
                    make_float4(a[2] + bb[2], a[3] + bb[3], a[4] + bb[4], a[5] + bb[5]);
                if (t4 == 12)
                    *(float4*)&Tf[tw][yy - 1][16] =
                        make_float4(a[6] + bb[6], a[7] + bb[7], a[8] + bb[8], a[9] + bb[9]);
            }
        }

        // ---- centers: slice s_k -> 6-deep register ring ----
        {
            const float ncm = rawm[sw][ty + 2][tx + 4];
            const float ncf = rawf[sw][ty + 2][tx + 4];
#pragma unroll
            for (int s2 = 5; s2 > 0; --s2) { cm[s2] = cm[s2 - 1]; cf[s2] = cf[s2 - 1]; }
            cm[0] = ncm; cf[0] = ncf;
        }

        // ---- y-phase: xs[(k-1)&1] (slice s_{k-1}) -> box[k&1] (lanes 96-255) ----
        if (tid >= 96 && k >= 1 && k <= ZSEG + 4) {
            const int ytid = tid - 96;             // 0..159
            const int x  = ytid & 15;
            const int c8 = ((ytid >> 4) & 1) * 8;  // 0 or 8
            const int f  = ytid >> 5;              // 0..4
            const float* xp = &xs[(k - 1) & 1][f][c8][x];   // row stride 16
            float v[12];
#pragma unroll
            for (int j = 0; j < 12; ++j) v[j] = xp[16 * j];
            float o[8];
            float s = v[0] + v[1] + v[2] + v[3] + v[4];
            o[0] = s;
#pragma unroll
            for (int j = 1; j < 8; ++j) { s += v[j + 4] - v[j - 1]; o[j] = s; }
            float* bp = &box[k & 1][x][f][c8];
            *(float4*)bp       = make_float4(o[0], o[1], o[2], o[3]);
            *(float4*)(bp + 4) = make_float4(o[4], o[5], o[6], o[7]);
        }

        // ---- ingest box[(k-1)&1] (2D sums of slice s_{k-2}) -> ring ----
        if (k >= 2) {
            const float* bq = &box[(k - 1) & 1][tx][0][ty];  // f-stride 20 dwords
            const float s0 = bq[0], s1 = bq[20], s2v = bq[40], s3 = bq[60], s4 = bq[80];
#pragma unroll
            for (int s = 0; s < 4; ++s)
#pragma unroll
                for (int f = 0; f < 5; ++f) ring[s][f] = ring[s + 1][f];
            ring[4][0] = s0; ring[4][1] = s1; ring[4][2] = s2v; ring[4][3] = s3; ring[4][4] = s4;
        }

        // ---- emit slice z = s_{k-4} = z0-6+k ----
        if (k >= 6) {
            float sum_m = 0.f, sum_f = 0.f, sum_mm = 0.f, sum_ff = 0.f, sum_mf = 0.f;
#pragma unroll
            for (int s = 0; s < 5; ++s) {
                sum_m  += ring[s][0];
                sum_f  += ring[s][1];
                sum_mm += ring[s][2];
                sum_ff += ring[s][3];
                sum_mf += ring[s][4];
            }
            const int z    = z0 - 6 + k;
            const int vidx = vbase + (k - 6) * SLICE;
            const int tsl  = (k + 1) % 5;     // T slot of slice z (written region k-4)
            const float mc = cm[4];           // center at z
            const float fc = cf[4];
            const float Tc = mc + fc;

            // gradient sums via T field (stored row r <-> raw row r+1)
            const float* tp = &Tf[tsl][ty + 1][tx + 1];   // raw row cy: {gx-1, gx+1}
            const float Txm = tp[0], Txp = tp[2];
            const float* tq = &Tf[tsl][ty][tx + 2];       // raw rows cy-1, cy+1
            const float Tym = tq[0], Typ = tq[40];

            float gsx, gsy, gsz;
            if (gx == 0)          gsx = Txp - Tc;
            else if (gx == WW-1)  gsx = Tc - Txm;
            else                  gsx = 0.5f * (Txp - Txm);
            if (gy == 0)          gsy = Typ - Tc;
            else if (gy == HH-1)  gsy = Tc - Tym;
            else                  gsy = 0.5f * (Typ - Tym);
            const float Tzm = cm[5] + cf[5], Tzp = cm[3] + cf[3];
            if (z == 0)           gsz = Tzp - Tc;
            else if (z == DD-1)   gsz = Tc - Tzm;
            else                  gsz = 0.5f * (Tzp - Tzm);

            const float u = ((um != 0) || (uf != 0)) ? 1.0f : 0.0f;

            const float npix = 125.0f;
            const float inv_npix = 1.0f / 125.0f;
            const float mean_m = sum_m * inv_npix;
            const float mean_f = sum_f * inv_npix;
            const float var_m = sum_mm - 2.0f * mean_m * sum_m + npix * mean_m * mean_m;
            const float var_f = sum_ff - 2.0f * mean_f * sum_f + npix * mean_f * mean_f;
            const float var_mf = var_m * var_f;
            const float cross = sum_mf - mean_f * sum_m - mean_m * sum_f + npix * mean_m * mean_f;
            const float mmc = mc - mean_m;
            const float fmc = fc - mean_f;
            const bool ok = (var_mf > 1e-5f) && (var_f > 1e-5f) && (fmc != 0.0f) && (mmc != 0.0f);
            float factor = 0.0f;
            if (ok) factor = 2.0f * cross / var_mf * (mmc - cross * fmc / var_f);

            const float nf = -factor * 0.5f * u;
            out[vidx]            = nf * gsz;   // ch 0: d/dD
            out[NVOX + vidx]     = nf * gsy;   // ch 1: d/dH
            out[2 * NVOX + vidx] = nf * gsx;   // ch 2: d/dW
        }
        // no trailing barrier: every cross-phase buffer pair is separated by
        // the single barrier at the top of the consuming region (see audit).
    }
}

extern "C" void kernel_launch(void* const* d_in, const int* in_sizes, int n_in,
                              void* d_out, int out_size, void* d_ws, size_t ws_size,
                              hipStream_t stream)
{
    const float* mimg  = (const float*)d_in[0];
    const float* fimg  = (const float*)d_in[1];
    const int*   mmask = (const int*)d_in[2];
    const int*   fmask = (const int*)d_in[3];
    float* out = (float*)d_out;

    dim3 grid(NBLK, 1, 1);   // 2304 blocks
    dim3 block(256, 1, 1);
    hipLaunchKernelGGL(ncc_forces_kernel, grid, block, 0, stream,
                       mimg, fimg, mmask, fmask, out);
}